// Round 2
// baseline (229.136 us; speedup 1.0000x reference)
//
#include <hip/hip_runtime.h>
#include <hip/hip_bf16.h>
#include <stdint.h>

typedef __bf16 bf16_t;
typedef __attribute__((ext_vector_type(8))) __bf16 bf16x8;
typedef __attribute__((ext_vector_type(4))) float f32x4;

// ---------------------------------------------------------------------------
// q8: exact re-implementation of reference to_float8.
// ---------------------------------------------------------------------------
__device__ __forceinline__ float q8(float v) {
    float a = __builtin_fabsf(v);
    float z = a + 1e-8f;
    int ei = ((__float_as_int(z) >> 23) & 0xff) - 127;
    ei = ei > 7 ? 7 : (ei < -7 ? -7 : ei);
    float p  = __int_as_float((ei + 127) << 23);
    float ip = __int_as_float((127 - ei) << 23);
    float m  = __builtin_fmaf(a, ip, -1.0f);
    float mq = __builtin_rintf(m * 8.0f) * 0.125f;
    float r  = (1.0f + mq) * p;
    return v < 0.0f ? -r : r;
}

__device__ __forceinline__ void gload_lds16(const bf16_t* g, bf16_t* l) {
    __builtin_amdgcn_global_load_lds(
        (__attribute__((address_space(1))) void*)(g),
        (__attribute__((address_space(3))) void*)(l), 16, 0, 0);
}

template<int N> __device__ __forceinline__ void vmwait() {
    if constexpr (N == 0)      asm volatile("s_waitcnt vmcnt(0)" ::: "memory");
    else if constexpr (N == 5) asm volatile("s_waitcnt vmcnt(5)" ::: "memory");
    else if constexpr (N == 6) asm volatile("s_waitcnt vmcnt(6)" ::: "memory");
    else if constexpr (N == 8) asm volatile("s_waitcnt vmcnt(8)" ::: "memory");
}

__device__ __forceinline__ bf16x8 cvt8(float4 a, float4 b) {
    bf16x8 o = { (bf16_t)a.x, (bf16_t)a.y, (bf16_t)a.z, (bf16_t)a.w,
                 (bf16_t)b.x, (bf16_t)b.y, (bf16_t)b.z, (bf16_t)b.w };
    return o;
}
__device__ __forceinline__ bf16x8 q8x8(float4 a, float4 b) {
    bf16x8 o = { (bf16_t)q8(a.x), (bf16_t)q8(a.y), (bf16_t)q8(a.z), (bf16_t)q8(a.w),
                 (bf16_t)q8(b.x), (bf16_t)q8(b.y), (bf16_t)q8(b.z), (bf16_t)q8(b.w) };
    return o;
}

// ---------------------------------------------------------------------------
// Fused pack kernel, 10240 blocks x 256 threads, 8 elems/thread, 16B stores.
// ---------------------------------------------------------------------------
__global__ void pack_all(const float* __restrict__ x, const float* __restrict__ u,
                         const float* __restrict__ A, const float* __restrict__ B,
                         const float* __restrict__ C,
                         bf16_t* __restrict__ XU, bf16_t* __restrict__ AB,
                         bf16_t* __restrict__ CQ) {
    const unsigned bid = blockIdx.x;
    const int tid = threadIdx.x;
    if (bid < 4096u) {
        size_t r = bid; int col = tid * 8;
        float4 v0 = *(const float4*)&x[r * 2048 + col];
        float4 v1 = *(const float4*)&x[r * 2048 + col + 4];
        *(bf16x8*)&XU[r * 3072 + col] = cvt8(v0, v1);
    } else if (bid < 6144u) {
        unsigned b = bid - 4096u;
        size_t r = b * 2 + (tid >> 7); int col = (tid & 127) * 8;
        float4 v0 = *(const float4*)&u[r * 1024 + col];
        float4 v1 = *(const float4*)&u[r * 1024 + col + 4];
        *(bf16x8*)&XU[r * 3072 + 2048 + col] = cvt8(v0, v1);
    } else if (bid < 8192u) {
        size_t r = bid - 6144u; int col = tid * 8;
        float4 v0 = *(const float4*)&A[r * 2048 + col];
        float4 v1 = *(const float4*)&A[r * 2048 + col + 4];
        *(bf16x8*)&AB[r * 3072 + col] = q8x8(v0, v1);
    } else if (bid < 9216u) {
        unsigned b = bid - 8192u;
        size_t r = b * 2 + (tid >> 7); int col = (tid & 127) * 8;
        float4 v0 = *(const float4*)&B[r * 1024 + col];
        float4 v1 = *(const float4*)&B[r * 1024 + col + 4];
        *(bf16x8*)&AB[r * 3072 + 2048 + col] = q8x8(v0, v1);
    } else {
        size_t r = bid - 9216u; int col = tid * 8;
        float4 v0 = *(const float4*)&C[r * 2048 + col];
        float4 v1 = *(const float4*)&C[r * 2048 + col + 4];
        *(bf16x8*)&CQ[r * 2048 + col] = q8x8(v0, v1);
    }
}

// ---------------------------------------------------------------------------
// GEMM (B^T): outf[i,j] = q8( sum_k A[i,k]*B[j,k] ), f32 out, optional bf16.
// Round-9: m201-style 8-phase port. BM=256, BN=128/64, BK=64, 512 thr,
// 8 waves (4M x 2N), wave tile 64 x (BN/2). Grid 16x16=256 for BOTH gemms.
//
//  * A staged as K=32 HALF-slots in a 4-slot ring sAr[4] (slot(t,s)=(2t+s)&3);
//    B staged as full K-tiles in a 3-ring sBr[3] (buf=t%3).
//  * 4 phases per K-tile, each: {ds_read frags; issue one half-tile
//    global_load_lds; s_barrier; lgkmcnt(0); setprio(1); 2*NI MFMA;
//    setprio(0); [counted vmcnt]; s_barrier}. Loads stay in flight ACROSS
//    barriers (T3+T4); vmcnt never drains to 0 in steady state.
//  * Stage schedule (per tile t): ph0: A(t+1,s1)  ph1: B(t+2)  ph2: A(t+2,s0).
//    Each stage targets a slot whose readers retired at the PREVIOUS phase's
//    closing barrier (WAR-safe), and gets ~6 phases of flight (>> HBM lat).
//  * Wait ledger (per-wave issue order ph0:2, ph1:BL, ph2:2 per tile):
//      MID  (ph1 tail): A(t,s1) [t-1 ph0] has 4+2*BL newer -> vmcnt(4+2BL)
//      END  (ph3 tail): A(t+1,s0) [t-1 ph2] has 4+BL newer -> vmcnt(4+BL)
//      (B(t+1) is older than both cutoffs.)  t<2 and t>=NT-2: vmcnt(0).
//  * A-slot swizzle: slot row r (256), 4 chunks c of 8 elems; LDS slot (r,c)
//    holds global chunk c ^ ((r>>1)&3): per-quad 8 distinct bank-starts,
//    2 rows each (2-way = free). B keeps the proven c ^ (r&7) scheme.
//  * ""::: "memory" after each s_barrier pins LDS reads/stages inside their
//    phase (raw s_barrier is not an LLVM memory fence).
//  * K-accumulation order (ascending 32-chunks) identical to the previously
//    passing kernels -> bit-identical outputs.
// LDS: gemm1 4*16K + 3*16K = 112 KB; gemm2 64K + 24K = 88 KB. 1 block/CU.
// ---------------------------------------------------------------------------
#define PHASE_CORE(i0, i1)                                                     \
    __builtin_amdgcn_s_barrier();                                              \
    asm volatile("s_waitcnt lgkmcnt(0)" ::: "memory");                         \
    __builtin_amdgcn_s_setprio(1);                                             \
    _Pragma("unroll")                                                          \
    for (int in = 0; in < NI; ++in)                                            \
        acc[i0][in] = __builtin_amdgcn_mfma_f32_16x16x32_bf16(af0, bfv[in],    \
                                                              acc[i0][in], 0, 0, 0); \
    _Pragma("unroll")                                                          \
    for (int in = 0; in < NI; ++in)                                            \
        acc[i1][in] = __builtin_amdgcn_mfma_f32_16x16x32_bf16(af1, bfv[in],    \
                                                              acc[i1][in], 0, 0, 0); \
    __builtin_amdgcn_s_setprio(0);

template<int BN, bool DUAL>
__global__ __launch_bounds__(512, 2)
void gemm_q8_8ph(const bf16_t* __restrict__ Ap, const bf16_t* __restrict__ Bp,
                 float* __restrict__ outf, bf16_t* __restrict__ outb,
                 int N, int K) {
    constexpr int BM = 256;
    constexpr int BK = 64;
    constexpr int NI = BN / 32;          // 4 (BN=128) or 2 (BN=64)
    constexpr int BL = BN / 64;          // B loads/thread/tile: 2 or 1
    constexpr int VM_MID = 4 + 2 * BL;   // 8 / 6
    constexpr int VM_END = 4 + BL;       // 6 / 5
    constexpr int ASLOT = BM * 32;       // 8192 elems = 16 KB
    constexpr int BBUF  = BN * 64;       // 8192 / 4096 elems

    __shared__ alignas(16) bf16_t sAr[4][ASLOT];
    __shared__ alignas(16) bf16_t sBr[3][BBUF];

    const int tid  = threadIdx.x;
    const int lane = tid & 63;
    const int wave = tid >> 6;       // 0..7
    const int wm   = wave & 3;       // 4 m-strips of 64 rows
    const int wn   = wave >> 2;      // 2 n-strips of BN/2
    const int ln16 = lane & 15;
    const int quad = lane >> 4;

    // XCD patch swizzle on the 16x16 block grid: xcd=b&7 owns a 8x4 patch
    const int b   = blockIdx.x;
    const int xcd = b & 7;
    const int g   = b >> 3;                 // 0..31
    const int bx  = (xcd & 1) * 8 + (g & 7);        // 0..15
    const int by  = (xcd >> 1) * 4 + (g >> 3);      // 0..15
    const int brow = by * BM;
    const int bcol = bx * BN;

    // ---- staging pointers ----
    // A half-slot streams: r = L>>2 (256 rows), c = L&3, src chunk c^((r>>1)&3)
    const bf16_t *pA0a, *pA0b, *pA1a, *pA1b;
    {
        int L0 = tid,       r0 = L0 >> 2, c0 = L0 & 3;
        int L1 = 512 + tid, r1 = L1 >> 2, c1 = L1 & 3;
        size_t ro0 = (size_t)(brow + r0) * K;
        size_t ro1 = (size_t)(brow + r1) * K;
        int cs0 = (c0 ^ ((r0 >> 1) & 3)) * 8;
        int cs1 = (c1 ^ ((r1 >> 1) & 3)) * 8;
        pA0a = Ap + ro0 + cs0;        pA0b = Ap + ro1 + cs1;        // s0 stream
        pA1a = Ap + ro0 + 32 + cs0;   pA1b = Ap + ro1 + 32 + cs1;   // s1 stream
    }
    // B stream: r = L>>3 (BN rows), c = L&7, src chunk c^(r&7)
    const bf16_t *pB0, *pB1 = nullptr;
    {
        int L = tid, r = L >> 3, c = L & 7;
        pB0 = Bp + (size_t)(bcol + r) * K + (c ^ (r & 7)) * 8;
    }
    if constexpr (BL == 2) {
        int L = 512 + tid, r = L >> 3, c = L & 7;
        pB1 = Bp + (size_t)(bcol + r) * K + (c ^ (r & 7)) * 8;
    }

    // ---- fragment LDS offsets (elements) ----
    int a_off[4];
#pragma unroll
    for (int im = 0; im < 4; ++im) {
        int r = wm * 64 + im * 16 + ln16;
        a_off[im] = (r * 4 + (quad ^ ((r >> 1) & 3))) * 8;
    }
    int b_off[NI][2];
#pragma unroll
    for (int in = 0; in < NI; ++in) {
        int r = wn * (BN / 2) + in * 16 + ln16;
#pragma unroll
        for (int s = 0; s < 2; ++s) {
            int cg = s * 4 + quad;
            b_off[in][s] = (r * 8 + (cg ^ (r & 7))) * 8;
        }
    }

    f32x4 acc[4][NI];
#pragma unroll
    for (int im = 0; im < 4; ++im)
#pragma unroll
        for (int in = 0; in < NI; ++in)
            acc[im][in] = (f32x4){0.f, 0.f, 0.f, 0.f};

    // ---- prologue: A(0,s0)->slot0, A(0,s1)->slot1, A(1,s0)->slot2,
    //                B(0)->sBr[0], B(1)->sBr[1]; full drain + publish.
    gload_lds16(pA0a, &sAr[0][wave * 512]);        pA0a += BK;
    gload_lds16(pA0b, &sAr[0][4096 + wave * 512]); pA0b += BK;
    gload_lds16(pA1a, &sAr[1][wave * 512]);        pA1a += BK;
    gload_lds16(pA1b, &sAr[1][4096 + wave * 512]); pA1b += BK;
    gload_lds16(pA0a, &sAr[2][wave * 512]);        pA0a += BK;
    gload_lds16(pA0b, &sAr[2][4096 + wave * 512]); pA0b += BK;
    gload_lds16(pB0, &sBr[0][wave * 512]);         pB0 += BK;
    if constexpr (BL == 2) { gload_lds16(pB1, &sBr[0][4096 + wave * 512]); pB1 += BK; }
    gload_lds16(pB0, &sBr[1][wave * 512]);         pB0 += BK;
    if constexpr (BL == 2) { gload_lds16(pB1, &sBr[1][4096 + wave * 512]); pB1 += BK; }
    vmwait<0>();
    __builtin_amdgcn_s_barrier();
    asm volatile("" ::: "memory");

    const int NT = K / BK;
    int bb = 0;                               // B ring index = t % 3
    for (int t = 0; t < NT; ++t) {
        const int sl0 = (t & 1) << 1;         // slot(t, s0): 0 or 2
        const int sl1 = sl0 | 1;              // slot(t, s1)
        const bool strong = (t < 2) | (t >= NT - 2);

        bf16x8 af0, af1, bfv[NI];

        // -------- phase 0: s=0, im {0,1}; stage A(t+1,s1)
        af0 = *(const bf16x8*)&sAr[sl0][a_off[0]];
        af1 = *(const bf16x8*)&sAr[sl0][a_off[1]];
#pragma unroll
        for (int in = 0; in < NI; ++in)
            bfv[in] = *(const bf16x8*)&sBr[bb][b_off[in][0]];
        if (t + 1 < NT) {
            const int sa = (sl0 + 3) & 3;
            gload_lds16(pA1a, &sAr[sa][wave * 512]);        pA1a += BK;
            gload_lds16(pA1b, &sAr[sa][4096 + wave * 512]); pA1b += BK;
        }
        PHASE_CORE(0, 1)
        __builtin_amdgcn_s_barrier();
        asm volatile("" ::: "memory");

        // -------- phase 1: s=0, im {2,3}; stage B(t+2); MID wait
        af0 = *(const bf16x8*)&sAr[sl0][a_off[2]];
        af1 = *(const bf16x8*)&sAr[sl0][a_off[3]];
        if (t + 2 < NT) {
            const int bs = (bb + 2 >= 3) ? bb - 1 : bb + 2;
            gload_lds16(pB0, &sBr[bs][wave * 512]);         pB0 += BK;
            if constexpr (BL == 2) { gload_lds16(pB1, &sBr[bs][4096 + wave * 512]); pB1 += BK; }
        }
        PHASE_CORE(2, 3)
        if (strong) vmwait<0>(); else vmwait<VM_MID>();
        __builtin_amdgcn_s_barrier();
        asm volatile("" ::: "memory");

        // -------- phase 2: s=1, im {0,1}; stage A(t+2,s0) into freed sl0
        af0 = *(const bf16x8*)&sAr[sl1][a_off[0]];
        af1 = *(const bf16x8*)&sAr[sl1][a_off[1]];
#pragma unroll
        for (int in = 0; in < NI; ++in)
            bfv[in] = *(const bf16x8*)&sBr[bb][b_off[in][1]];
        if (t + 2 < NT) {
            gload_lds16(pA0a, &sAr[sl0][wave * 512]);        pA0a += BK;
            gload_lds16(pA0b, &sAr[sl0][4096 + wave * 512]); pA0b += BK;
        }
        PHASE_CORE(0, 1)
        __builtin_amdgcn_s_barrier();
        asm volatile("" ::: "memory");

        // -------- phase 3: s=1, im {2,3}; END wait
        af0 = *(const bf16x8*)&sAr[sl1][a_off[2]];
        af1 = *(const bf16x8*)&sAr[sl1][a_off[3]];
        PHASE_CORE(2, 3)
        if (strong) vmwait<0>(); else vmwait<VM_END>();
        __builtin_amdgcn_s_barrier();
        asm volatile("" ::: "memory");

        bb = (bb == 2) ? 0 : bb + 1;
    }

    // ---- epilogue: C/D layout col = lane&15, row = quad*4 + reg
    const int rbase = quad * 4;
#pragma unroll
    for (int im = 0; im < 4; ++im) {
#pragma unroll
        for (int in = 0; in < NI; ++in) {
            int gm = brow + wm * 64 + im * 16 + rbase;
            int gn = bcol + wn * (BN / 2) + in * 16 + ln16;
#pragma unroll
            for (int r = 0; r < 4; ++r) {
                float v = q8(acc[im][in][r]);
                outf[(size_t)(gm + r) * N + gn] = v;
                if (DUAL) outb[(size_t)(gm + r) * N + gn] = (bf16_t)v;
            }
        }
    }
}

// ---------------------------------------------------------------------------
extern "C" void kernel_launch(void* const* d_in, const int* in_sizes, int n_in,
                              void* d_out, int out_size, void* d_ws, size_t ws_size,
                              hipStream_t stream) {
    const float* x = (const float*)d_in[0];   // 4096 x 2048
    const float* u = (const float*)d_in[1];   // 4096 x 1024
    const float* A = (const float*)d_in[2];   // 2048 x 2048
    const float* B = (const float*)d_in[3];   // 2048 x 1024
    const float* C = (const float*)d_in[4];   // 1024 x 2048

    float* outf = (float*)d_out;
    float* xnf  = outf;                                 // 4096 x 2048 f32
    float* yf   = outf + (size_t)4096 * 2048;           // 4096 x 1024 f32

    uint8_t* ws = (uint8_t*)d_ws;
    bf16_t* XU = (bf16_t*)ws;                                            // 24 MB
    bf16_t* AB = (bf16_t*)(ws + (size_t)25165824);                       // 12 MB
    bf16_t* CQ = (bf16_t*)(ws + (size_t)25165824 + 12582912);            //  4 MB
    bf16_t* XN = (bf16_t*)(ws + (size_t)25165824 + 12582912 + 4194304);  // 16 MB

    pack_all<<<dim3(10240), 256, 0, stream>>>(x, u, A, B, C, XU, AB, CQ);

    // x_next = q8([x|u] @ [Aq|Bq]^T): M=4096 N=2048 K=3072; grid 16x16
    gemm_q8_8ph<128, true><<<dim3(256), 512, 0, stream>>>(
        XU, AB, xnf, XN, 2048, 3072);
    // y = q8(x_next @ Cq^T): M=4096 N=1024 K=2048; grid 16x16
    gemm_q8_8ph<64, false><<<dim3(256), 512, 0, stream>>>(
        XN, CQ, yf, nullptr, 1024, 2048);
}